// Round 1
// baseline (302.552 us; speedup 1.0000x reference)
//
#include <hip/hip_runtime.h>
#include <hip/hip_bf16.h>

#define FIN 4096
#define FOUT 4096
#define HEADS 4
#define ROWS_PER_HEAD (FOUT / HEADS)  // 1024
#define M_DIM 4096                    // 2*2048 flattened batch*seq

typedef __attribute__((ext_vector_type(8))) short bf16x8;   // 8 bf16 = 4 VGPRs
typedef __attribute__((ext_vector_type(4))) float floatx4;  // MFMA accum

#define CAST_BLOCKS ((M_DIM * FIN) / (256 * 8))      // 8192
#define TRANS_BLOCKS ((FOUT * FIN / 8) / 256)        // 8192

// ---------------------------------------------------------------------------
// Kernel 1 (merged prep, unchanged from R5-verified): blocks [0, CAST_BLOCKS)
// cast inp fp32->bf16; blocks [CAST_BLOCKS, +TRANS_BLOCKS) compute
// W_i = conv3x3 + bias + sigmoid(sk)*W (fp32 in, bf16 out).
// ---------------------------------------------------------------------------
__global__ __launch_bounds__(256) void prep(
    const float* __restrict__ x,    // activations [M_DIM][FIN]
    __hip_bfloat16* __restrict__ y, // bf16 activations out
    const float* __restrict__ W,
    const float* __restrict__ cw,   // [HEADS][3][3]
    const float* __restrict__ cb,   // [HEADS]
    const float* __restrict__ sk,   // [HEADS]
    __hip_bfloat16* __restrict__ Wt) {
  if (blockIdx.x < CAST_BLOCKS) {
    int idx = blockIdx.x * 256 + threadIdx.x;  // one per 8 elements
    const float4* xv = (const float4*)x;
    float4 a = xv[idx * 2];
    float4 b = xv[idx * 2 + 1];
    __hip_bfloat16 t[8];
    t[0] = __float2bfloat16(a.x); t[1] = __float2bfloat16(a.y);
    t[2] = __float2bfloat16(a.z); t[3] = __float2bfloat16(a.w);
    t[4] = __float2bfloat16(b.x); t[5] = __float2bfloat16(b.y);
    t[6] = __float2bfloat16(b.z); t[7] = __float2bfloat16(b.w);
    *(bf16x8*)(&y[(size_t)idx * 8]) = *(bf16x8*)t;
    return;
  }

  int gid = (blockIdx.x - CAST_BLOCKS) * 256 + threadIdx.x;
  int o = gid >> 9;                          // output row (FIN/8 = 512)
  int fs = (gid & 511) << 3;                 // fin start, multiple of 8
  int h = o >> 10;                           // head
  int r = o & (ROWS_PER_HEAD - 1);

  float kk[3][3];
#pragma unroll
  for (int i = 0; i < 3; i++)
#pragma unroll
    for (int j = 0; j < 3; j++) kk[i][j] = cw[h * 9 + i * 3 + j];
  float sig = 1.0f / (1.0f + __expf(-sk[h]));

  float acc[8];
#pragma unroll
  for (int j = 0; j < 8; j++) acc[j] = cb[h];

#pragma unroll
  for (int dr = -1; dr <= 1; dr++) {
    int rr = r + dr;
    if (rr < 0 || rr >= ROWS_PER_HEAD) continue;
    const float* rp = W + ((size_t)(h * ROWS_PER_HEAD + rr)) * FIN + fs;
    float a[10];
    float4 v0 = *(const float4*)rp;
    float4 v1 = *(const float4*)(rp + 4);
    a[1] = v0.x; a[2] = v0.y; a[3] = v0.z; a[4] = v0.w;
    a[5] = v1.x; a[6] = v1.y; a[7] = v1.z; a[8] = v1.w;
    a[0] = (fs > 0) ? rp[-1] : 0.0f;
    a[9] = (fs + 8 < FIN) ? rp[8] : 0.0f;
#pragma unroll
    for (int j = 0; j < 8; j++)
      acc[j] += kk[dr + 1][0] * a[j] + kk[dr + 1][1] * a[j + 1] +
                kk[dr + 1][2] * a[j + 2];
    if (dr == 0) {
#pragma unroll
      for (int j = 0; j < 8; j++) acc[j] += sig * a[j + 1];
    }
  }
  __hip_bfloat16 t[8];
#pragma unroll
  for (int j = 0; j < 8; j++) t[j] = __float2bfloat16(acc[j]);
  *(bf16x8*)(&Wt[(size_t)o * FIN + fs]) = *(bf16x8*)t;
}

// ---------------------------------------------------------------------------
// Kernel 2: C[m][n] = sum_k A[m][k] * B[n][k]  (NT GEMM, bf16 in, FP32 out)
// R8: 256x256 tile, BK=64, 512 threads (2x4 waves), 8-phase schedule with
// counted vmcnt (T3+T4) + setprio (T5). LDS swizzle = proven chunk-XOR
// (slot s of row r holds global chunk s^(r&7)); SQ_LDS_BANK_CONFLICT was 0.
//
// Per-wave output 128x64 with STRIDED fragments: m-frag i at row wr*16+i*32,
// n-frag j at col wn*16+j*64 -> each phase's quadrant reads exactly ONE
// A-half and ONE B-half of the 256-row tile across ALL waves.
//
// Per K-tile t (buf = t&1), 4 phases, quadrants (mh,nh)=(0,0),(0,1),(1,1),(1,0):
//   q1: ds_read A-h0 + B-h0 frags; STAGE A[t+1]-h1 -> nbuf; BAR; MMA; BAR
//   q2: ds_read B-h1 frags;        STAGE B[t+1]-h0 -> nbuf; BAR; MMA; BAR
//   q3: ds_read A-h1 frags;        STAGE A[t+2]-h0 -> buf;  BAR; MMA; BAR
//   q4: (all frags in regs);       STAGE B[t+2]-h1 -> buf;  BAR; MMA;
//       s_waitcnt vmcnt(4); BAR
// LDS half deaths: A-h0@q1, B-h0@q1 (kept in regs to q4), B-h1@q2, A-h1@q3;
// every stage lands in a half whose last reader passed a barrier earlier.
// vmcnt(4) leaves exactly tile t+2's A-h0/B-h1 (4 loads) in flight -- never
// drains to 0 in the main loop. Last two tiles peeled to keep counts exact.
// ---------------------------------------------------------------------------
__device__ static inline void gload_lds16(const void* g, void* l) {
  __builtin_amdgcn_global_load_lds(
      (const __attribute__((address_space(1))) void*)g,
      (__attribute__((address_space(3))) void*)l, 16, 0, 0);
}

#define BK 64
#define NT (FIN / BK)  // 64 K-tiles

__global__ __launch_bounds__(512, 2) void gemm_nt(
    const __hip_bfloat16* __restrict__ A,  // [M][K]
    const __hip_bfloat16* __restrict__ B,  // [N][K]  (= W_i, row-major)
    float* __restrict__ C,                 // [M][N] fp32
    int M, int N, int K) {
  __shared__ __hip_bfloat16 As[2][2][128 * BK];  // [buf][half][row*64] 64 KB
  __shared__ __hip_bfloat16 Bs[2][2][128 * BK];  // 64 KB

  const int tid = threadIdx.x;
  const int lane = tid & 63;
  const int wave = tid >> 6;   // 0..7
  const int wr = wave >> 2;    // 0..1  (WARPS_M = 2)
  const int wn = wave & 3;     // 0..3  (WARPS_N = 4)
  const int fr = lane & 15;    // fragment row
  const int quad = lane >> 4;  // k-chunk selector
  const int sel = fr & 7;      // swizzle selector
  const int tile_m = blockIdx.y * 256;
  const int tile_n = blockIdx.x * 256;

  const __hip_bfloat16* At = A + (size_t)tile_m * K;  // SGPR base
  const __hip_bfloat16* Bt = B + (size_t)tile_n * K;

  // Per-thread staging invariants: chunk position p = c*512+tid;
  // row=p>>3, slot=p&7 holds global chunk g=slot^(row&7).
  int soff[2], doff[2];
#pragma unroll
  for (int c = 0; c < 2; c++) {
    int p = c * 512 + tid;
    int row = p >> 3;
    int g = (p & 7) ^ (row & 7);
    soff[c] = row * K + g * 8;  // elems; < 2^21, fits int
    doff[c] = p * 8;            // elems into half-buffer
  }
  // Fragment read invariants (local rows are all == fr mod 8 -> sel works).
  int aro[4], bro[2], co[2];
#pragma unroll
  for (int u = 0; u < 4; u++) aro[u] = (wr * 16 + u * 32 + fr) * 64;
#pragma unroll
  for (int j = 0; j < 2; j++) bro[j] = (wn * 16 + j * 64 + fr) * 64;
#pragma unroll
  for (int kk = 0; kk < 2; kk++) co[kk] = ((kk * 4 + quad) ^ sel) * 8;

  floatx4 acc[8][4];
#pragma unroll
  for (int i = 0; i < 8; i++)
#pragma unroll
    for (int j = 0; j < 4; j++) acc[i][j] = (floatx4){0.f, 0.f, 0.f, 0.f};

  bf16x8 af[4][2];     // A frags: [u][kk] for current m-half
  bf16x8 bf[2][2][2];  // B frags: [nh][jh][kk], both halves held

#define STAGE(GBASE, LARR, TILE, BUF, HALF)                              \
  do {                                                                   \
    const __hip_bfloat16* _s =                                           \
        GBASE + (size_t)(HALF) * 128 * K + (size_t)(TILE) * BK;          \
    __hip_bfloat16* _d = &LARR[BUF][HALF][0];                            \
    _Pragma("unroll") for (int _c = 0; _c < 2; _c++) {                   \
      gload_lds16(_s + soff[_c], _d + doff[_c]);                         \
    }                                                                    \
  } while (0)

#define LOADA(BUF, MH)                                                   \
  do {                                                                   \
    const __hip_bfloat16* _b = &As[BUF][MH][0];                          \
    _Pragma("unroll") for (int _u = 0; _u < 4; _u++) {                   \
      _Pragma("unroll") for (int _kk = 0; _kk < 2; _kk++) {              \
        af[_u][_kk] = *(const bf16x8*)&_b[aro[_u] + co[_kk]];            \
      }                                                                  \
    }                                                                    \
  } while (0)

#define LOADB(BUF, NH)                                                   \
  do {                                                                   \
    const __hip_bfloat16* _b = &Bs[BUF][NH][0];                          \
    _Pragma("unroll") for (int _j = 0; _j < 2; _j++) {                   \
      _Pragma("unroll") for (int _kk = 0; _kk < 2; _kk++) {              \
        bf[NH][_j][_kk] = *(const bf16x8*)&_b[bro[_j] + co[_kk]];        \
      }                                                                  \
    }                                                                    \
  } while (0)

#define MMA(MH, NH)                                                      \
  do {                                                                   \
    __builtin_amdgcn_s_setprio(1);                                       \
    _Pragma("unroll") for (int _kk = 0; _kk < 2; _kk++) {                \
      _Pragma("unroll") for (int _u = 0; _u < 4; _u++) {                 \
        _Pragma("unroll") for (int _j = 0; _j < 2; _j++) {               \
          acc[(MH) * 4 + _u][(NH) * 2 + _j] =                            \
              __builtin_amdgcn_mfma_f32_16x16x32_bf16(                   \
                  af[_u][_kk], bf[NH][_j][_kk],                          \
                  acc[(MH) * 4 + _u][(NH) * 2 + _j], 0, 0, 0);           \
        }                                                                \
      }                                                                  \
    }                                                                    \
    __builtin_amdgcn_s_setprio(0);                                       \
  } while (0)

#define BAR() __builtin_amdgcn_s_barrier()
#define WAITVM(N) asm volatile("s_waitcnt vmcnt(" #N ")" ::: "memory")

  // ---- Prologue: tile0 fully + tile1 A-h0,B-h1 (issue order matters).
  STAGE(At, As, 0, 0, 0);  // tile0 A-h0
  STAGE(Bt, Bs, 0, 0, 1);  // tile0 B-h1
  STAGE(At, As, 0, 0, 1);  // tile0 A-h1
  STAGE(Bt, Bs, 0, 0, 0);  // tile0 B-h0
  STAGE(At, As, 1, 1, 0);  // tile1 A-h0
  STAGE(Bt, Bs, 1, 1, 1);  // tile1 B-h1
  WAITVM(4);               // tile0's 8 loads complete; tile1's 4 in flight
  BAR();

  // ---- Main loop: tiles 0 .. NT-3 (all stages unconditional).
#pragma unroll 2
  for (int t = 0; t < NT - 2; ++t) {
    const int buf = t & 1;
    const int nbuf = buf ^ 1;
    // q1: (mh0, nh0)
    LOADA(buf, 0);
    LOADB(buf, 0);
    STAGE(At, As, t + 1, nbuf, 1);
    BAR();
    MMA(0, 0);
    BAR();
    // q2: (mh0, nh1)
    LOADB(buf, 1);
    STAGE(Bt, Bs, t + 1, nbuf, 0);
    BAR();
    MMA(0, 1);
    BAR();
    // q3: (mh1, nh1)
    LOADA(buf, 1);
    STAGE(At, As, t + 2, buf, 0);
    BAR();
    MMA(1, 1);
    BAR();
    // q4: (mh1, nh0) -- frags already in regs
    STAGE(Bt, Bs, t + 2, buf, 1);
    BAR();
    MMA(1, 0);
    WAITVM(4);  // everything through this tile's q2 stage complete
    BAR();
  }

  // ---- Tile NT-2 (buf=0, nbuf=1): stage only tile NT-1's A-h1/B-h0.
  {
    LOADA(0, 0);
    LOADB(0, 0);
    STAGE(At, As, NT - 1, 1, 1);
    BAR();
    MMA(0, 0);
    BAR();
    LOADB(0, 1);
    STAGE(Bt, Bs, NT - 1, 1, 0);
    BAR();
    MMA(0, 1);
    BAR();
    LOADA(0, 1);
    BAR();
    MMA(1, 1);
    BAR();
    BAR();
    MMA(1, 0);
    WAITVM(0);  // drain: tile NT-1 fully staged
    BAR();
  }
  // ---- Tile NT-1 (buf=1): no stages, no waits needed.
  {
    LOADA(1, 0);
    LOADB(1, 0);
    BAR();
    MMA(0, 0);
    BAR();
    LOADB(1, 1);
    BAR();
    MMA(0, 1);
    BAR();
    LOADA(1, 1);
    BAR();
    MMA(1, 1);
    BAR();
    BAR();
    MMA(1, 0);
  }

#undef STAGE
#undef LOADA
#undef LOADB
#undef MMA
#undef BAR
#undef WAITVM

  // ---- Epilogue: C/D layout col = lane&15, row = quad*4 + reg.
#pragma unroll
  for (int i = 0; i < 8; i++) {
    int mb = tile_m + wr * 16 + i * 32 + quad * 4;
#pragma unroll
    for (int j = 0; j < 4; j++) {
      int n = tile_n + wn * 16 + j * 64 + fr;
#pragma unroll
      for (int r = 0; r < 4; r++) {
        C[(size_t)(mb + r) * N + n] = acc[i][j][r];
      }
    }
  }
}

// ---------------------------------------------------------------------------
extern "C" void kernel_launch(void* const* d_in, const int* in_sizes, int n_in,
                              void* d_out, int out_size, void* d_ws,
                              size_t ws_size, hipStream_t stream) {
  const float* inp = (const float*)d_in[0];     // [2,2048,4096] fp32
  const float* W = (const float*)d_in[1];       // [4096,4096] fp32
  const float* conv_w = (const float*)d_in[2];  // [4,1,3,3] fp32
  const float* conv_b = (const float*)d_in[3];  // [4] fp32
  const float* sk_wt = (const float*)d_in[4];   // [4,1,1] fp32
  float* out = (float*)d_out;                   // [2,2048,4096] fp32

  __hip_bfloat16* Wt = (__hip_bfloat16*)d_ws;   // 32 MB
  __hip_bfloat16* Ab =
      (__hip_bfloat16*)((char*)d_ws + (size_t)(32u << 20));  // next 32 MB

  // 1) merged prep: cast activations + transform weight, one launch
  prep<<<CAST_BLOCKS + TRANS_BLOCKS, 256, 0, stream>>>(inp, Ab, W, conv_w,
                                                       conv_b, sk_wt, Wt);
  // 2) out[m][n] = sum_k Ab[m][k] * Wt[n][k]  (256x256 tiles, 8-phase)
  dim3 grid(FOUT / 256, M_DIM / 256);
  gemm_nt<<<grid, 512, 0, stream>>>(Ab, Wt, out, M_DIM, FOUT, FIN);
}